// Round 4
// baseline (161.310 us; speedup 1.0000x reference)
//
#include <hip/hip_runtime.h>
#include <math.h>

// Problem constants
constexpr int kB = 2;
constexpr int kC = 128;
constexpr int kN = 784;
constexpr float kInvT = 1.0f / 11.313708498984761f;  // 1/sqrt(C)
constexpr float kInvC = 1.0f / 128.0f;

__device__ inline float wave_max(float v) {
#pragma unroll
    for (int o = 32; o > 0; o >>= 1) v = fmaxf(v, __shfl_xor(v, o, 64));
    return v;
}
__device__ inline float wave_sum(float v) {
#pragma unroll
    for (int o = 32; o > 0; o >>= 1) v += __shfl_xor(v, o, 64);
    return v;
}

// ================= Kernel 1 (fused): attn = softmax_q( mean_c |q/T - k| ) =================
// Block = (b, 7 k-rows). Grid 224. No LDS for q: thread t owns q-cols [4t,4t+4)
// (t<196) read as coalesced float4 directly from global (L2-resident, 0.4 MB/batch).
// k-tile (7x128) in 4 KB LDS, broadcast reads. acc[7][4] in regs; softmax fused.
// Also zeroes the `out` region (bmm accumulates with atomics afterwards).
constexpr int KT = 7;
constexpr int KBLK = kN / KT;  // 112 blocks per batch

__global__ __launch_bounds__(256) void attn_fused(const float* __restrict__ qg,
                                                  const float* __restrict__ kg,
                                                  float* __restrict__ attn,
                                                  float* __restrict__ out_zero) {
    const int b  = blockIdx.x / KBLK;
    const int k0 = (blockIdx.x % KBLK) * KT;
    const int t  = threadIdx.x;

    // ---- zero the out region (one guarded float4 per thread; grid covers it) ----
    {
        const int idx = blockIdx.x * 256 + t;
        if (idx < (kB * kC * kN) / 4)
            reinterpret_cast<float4*>(out_zero)[idx] = make_float4(0.f, 0.f, 0.f, 0.f);
    }

    __shared__ float ks[kC][8];       // k-tile, padded 7->8 for b128 reads
    __shared__ float redm[4][KT];
    __shared__ float reds[4][KT];

    const float* kb = kg + (size_t)b * kC * kN;
    const float* qb = qg + (size_t)b * kC * kN;

    for (int i = t; i < kC * 8; i += 256) {
        const int c = i >> 3, kk = i & 7;
        ks[c][kk] = (kk < KT) ? kb[(size_t)c * kN + k0 + kk] : 0.0f;
    }
    __syncthreads();

    const bool act = t < (kN / 4);            // 196 active threads
    const int qoff = min(4 * t, kN - 4);      // clamp keeps inactive lanes in-bounds
    const float* qp = qb + qoff;

    float acc[KT][4];
#pragma unroll
    for (int kk = 0; kk < KT; ++kk)
#pragma unroll
        for (int j = 0; j < 4; ++j) acc[kk][j] = 0.0f;

#pragma unroll 4
    for (int c = 0; c < kC; ++c) {
        const float4 qv = *reinterpret_cast<const float4*>(qp + (size_t)c * kN);
        const float4 ka = *reinterpret_cast<const float4*>(&ks[c][0]);
        const float4 kb4 = *reinterpret_cast<const float4*>(&ks[c][4]);
        const float qf[4] = {qv.x, qv.y, qv.z, qv.w};
        const float kf[KT] = {ka.x, ka.y, ka.z, ka.w, kb4.x, kb4.y, kb4.z};
#pragma unroll
        for (int kk = 0; kk < KT; ++kk)
#pragma unroll
            for (int j = 0; j < 4; ++j)
                acc[kk][j] += fabsf(fmaf(qf[j], kInvT, -kf[kk]));  // v_fma + v_add(|x|)
    }

    // ---- softmax over q per k-row (raw sums; mean folded via kInvC) ----
    const int lane = t & 63, wid = t >> 6;

#pragma unroll
    for (int kk = 0; kk < KT; ++kk) {
        float lm = act ? fmaxf(fmaxf(acc[kk][0], acc[kk][1]),
                               fmaxf(acc[kk][2], acc[kk][3]))
                       : -1e30f;
        lm = wave_max(lm);
        if (lane == 0) redm[wid][kk] = lm;
    }
    __syncthreads();

    float m[KT];
#pragma unroll
    for (int kk = 0; kk < KT; ++kk)
        m[kk] = fmaxf(fmaxf(redm[0][kk], redm[1][kk]),
                      fmaxf(redm[2][kk], redm[3][kk]));

#pragma unroll
    for (int kk = 0; kk < KT; ++kk) {
        float ls = 0.0f;
#pragma unroll
        for (int j = 0; j < 4; ++j) {
            const float p = __expf((acc[kk][j] - m[kk]) * kInvC);
            acc[kk][j] = p;
            ls += p;
        }
        ls = act ? ls : 0.0f;   // mask garbage lanes
        ls = wave_sum(ls);
        if (lane == 0) reds[wid][kk] = ls;
    }
    __syncthreads();

    if (act) {
#pragma unroll
        for (int kk = 0; kk < KT; ++kk) {
            const float inv = 1.0f / (reds[0][kk] + reds[1][kk] +
                                      reds[2][kk] + reds[3][kk]);
            float4 o = make_float4(acc[kk][0] * inv, acc[kk][1] * inv,
                                   acc[kk][2] * inv, acc[kk][3] * inv);
            *reinterpret_cast<float4*>(
                attn + ((size_t)b * kN + k0 + kk) * kN + 4 * t) = o;
        }
    }
}

// ================= Kernel 2: out[b,c,k] += sum_q v[b,c,q] * attn[b,k,q] =================
// 64c x 64k tile, 4c x 4k per thread, qsplit 14 (56 q each, 2 chunks of 28).
// Grid = 2b * 2ct * 13kt * 14qs = 728 (~2.8 blocks/CU). Conflict-free transposed
// staging (float4 global read + scalar LDS writes, 2-way bank pattern = free).
constexpr int BKT = 64;
constexpr int NKT2 = (kN + BKT - 1) / BKT;  // 13
constexpr int QSP = 14;
constexpr int QPB = kN / QSP;               // 56
constexpr int QCH = 28;
constexpr int BSTR = 68;

__global__ __launch_bounds__(256) void bmm_kernel(const float* __restrict__ vg,
                                                  const float* __restrict__ attn,
                                                  float* __restrict__ out) {
    int bid = blockIdx.x;
    const int qs = bid % QSP;   bid /= QSP;
    const int kt = bid % NKT2;  bid /= NKT2;
    const int ct = bid & 1;     bid >>= 1;
    const int b  = bid;
    const int k0 = kt * BKT;
    const int c0 = ct * 64;
    const int qb0 = qs * QPB;
    const int t  = threadIdx.x;

    __shared__ float vT[QCH][BSTR];
    __shared__ float aT[QCH][BSTR];

    const int cc = t >> 2;        // staging row 0..63
    const int j1 = t & 3;         // q-float4 group 0..3
    const int j2 = j1 + 4;        // 4..7 (valid if <7)
    const int c0l = (t & 15) << 2;
    const int k0l = (t >> 4) << 2;

    float acc[4][4];
#pragma unroll
    for (int i = 0; i < 4; ++i)
#pragma unroll
        for (int j = 0; j < 4; ++j) acc[i][j] = 0.0f;

    const float* vb = vg + ((size_t)b * kC + c0) * kN;
    const float* ab = attn + (size_t)b * kN * kN;
    const int krow_st = min(k0 + cc, kN - 1);  // clamped pad rows never stored

    for (int qc = 0; qc < QPB; qc += QCH) {
        const int q0 = qb0 + qc;
        // prefetch (overlaps previous chunk's compute)
        const float4 vv1 = *reinterpret_cast<const float4*>(vb + (size_t)cc * kN + q0 + 4 * j1);
        const float4 av1 = *reinterpret_cast<const float4*>(ab + (size_t)krow_st * kN + q0 + 4 * j1);
        float4 vv2, av2;
        const bool has2 = (j2 < 7);
        if (has2) {
            vv2 = *reinterpret_cast<const float4*>(vb + (size_t)cc * kN + q0 + 4 * j2);
            av2 = *reinterpret_cast<const float4*>(ab + (size_t)krow_st * kN + q0 + 4 * j2);
        }
        __syncthreads();  // previous chunk's LDS reads done
        {
            const int r1 = 4 * j1;
            vT[r1 + 0][cc] = vv1.x; vT[r1 + 1][cc] = vv1.y;
            vT[r1 + 2][cc] = vv1.z; vT[r1 + 3][cc] = vv1.w;
            aT[r1 + 0][cc] = av1.x; aT[r1 + 1][cc] = av1.y;
            aT[r1 + 2][cc] = av1.z; aT[r1 + 3][cc] = av1.w;
            if (has2) {
                const int r2 = 4 * j2;
                vT[r2 + 0][cc] = vv2.x; vT[r2 + 1][cc] = vv2.y;
                vT[r2 + 2][cc] = vv2.z; vT[r2 + 3][cc] = vv2.w;
                aT[r2 + 0][cc] = av2.x; aT[r2 + 1][cc] = av2.y;
                aT[r2 + 2][cc] = av2.z; aT[r2 + 3][cc] = av2.w;
            }
        }
        __syncthreads();

#pragma unroll
        for (int qq = 0; qq < QCH; ++qq) {
            const float4 vf4 = *reinterpret_cast<const float4*>(&vT[qq][c0l]);
            const float4 af4 = *reinterpret_cast<const float4*>(&aT[qq][k0l]);
            const float vf[4] = {vf4.x, vf4.y, vf4.z, vf4.w};
            const float af[4] = {af4.x, af4.y, af4.z, af4.w};
#pragma unroll
            for (int i = 0; i < 4; ++i)
#pragma unroll
                for (int j = 0; j < 4; ++j) acc[i][j] += vf[i] * af[j];
        }
    }

#pragma unroll
    for (int i = 0; i < 4; ++i) {
        const int c = c0 + c0l + i;
#pragma unroll
        for (int j = 0; j < 4; ++j) {
            const int krow = k0 + k0l + j;
            if (krow < kN)
                atomicAdd(&out[((size_t)b * kC + c) * kN + krow], acc[i][j]);
        }
    }
}

extern "C" void kernel_launch(void* const* d_in, const int* in_sizes, int n_in,
                              void* d_out, int out_size, void* d_ws, size_t ws_size,
                              hipStream_t stream) {
    const float* q = (const float*)d_in[0];
    const float* k = (const float*)d_in[1];
    const float* v = (const float*)d_in[2];

    float* out  = (float*)d_out;               // [B, C, N]
    float* attn = out + (size_t)kB * kC * kN;  // [B, N, N]

    // d_ws intentionally unused. out is zeroed inside attn_fused (stream-ordered
    // before bmm_kernel's atomics).
    attn_fused<<<kB * KBLK, 256, 0, stream>>>(q, k, attn, out);
    bmm_kernel<<<kB * 2 * NKT2 * QSP, 256, 0, stream>>>(v, attn, out);
}

// Round 5
// 131.207 us; speedup vs baseline: 1.2294x; 1.2294x over previous
//
#include <hip/hip_runtime.h>
#include <math.h>

// Problem constants
constexpr int kB = 2;
constexpr int kC = 128;
constexpr int kN = 784;
constexpr float kInvT = 1.0f / 11.313708498984761f;  // 1/sqrt(C)
constexpr float kInvC = 1.0f / 128.0f;

__device__ inline float wave_max(float v) {
#pragma unroll
    for (int o = 32; o > 0; o >>= 1) v = fmaxf(v, __shfl_xor(v, o, 64));
    return v;
}
__device__ inline float wave_sum(float v) {
#pragma unroll
    for (int o = 32; o > 0; o >>= 1) v += __shfl_xor(v, o, 64);
    return v;
}

// ================= Kernel 1: D[b,k,q] = sum_c |q[c,q]/T - k[c,k]| (raw sums) =================
// 32k x 64q tile, FULL c=128 in LDS (53.2 KB -> 3 blocks/CU). Grid 2*25*13 = 650
// (~2.5 blocks/CU -> ~10 waves/CU). Thread: 2k x 4q; per c-iter 1 ds_read_b64 (k,
// 16-way broadcast) + 1 ds_read_b128 (q) = ~18 LDS-cyc vs 32 VALU-cyc -> VALU-bound.
// Also zeroes `out` (bmm accumulates atomically afterwards).
constexpr int TK = 32;
constexpr int TQ = 64;
constexpr int NKT = (kN + TK - 1) / TK;  // 25
constexpr int NQT = (kN + TQ - 1) / TQ;  // 13
constexpr int KSTR = 36;                 // 32+4 pad
constexpr int QSTR = 68;                 // 64+4 pad

__global__ __launch_bounds__(256) void dist_kernel(const float* __restrict__ qg,
                                                   const float* __restrict__ kg,
                                                   float* __restrict__ D,
                                                   float* __restrict__ out_zero) {
    int bid = blockIdx.x;
    const int qt = bid % NQT; bid /= NQT;
    const int kt = bid % NKT; bid /= NKT;
    const int b  = bid;
    const int k0 = kt * TK;
    const int q0 = qt * TQ;
    const int t  = threadIdx.x;

    // ---- zero the out region (grid*256 threads cover 100352 float4s easily) ----
    {
        const int idx = blockIdx.x * 256 + t;
        if (idx < (kB * kC * kN) / 4)
            reinterpret_cast<float4*>(out_zero)[idx] = make_float4(0.f, 0.f, 0.f, 0.f);
    }

    __shared__ float ks[kC][KSTR];  // 18.4 KB
    __shared__ float qs[kC][QSTR];  // 34.8 KB

    const float* kb = kg + (size_t)b * kC * kN;
    const float* qb = qg + (size_t)b * kC * kN;

    // Stage k-tile: 128 rows x 8 float4 = 1024 items, 4 iters.
#pragma unroll
    for (int i = t; i < kC * 8; i += 256) {
        const int c  = i >> 3;
        const int x4 = (i & 7) << 2;
        *reinterpret_cast<float4*>(&ks[c][x4]) =
            *reinterpret_cast<const float4*>(kb + (size_t)c * kN + min(k0 + x4, kN - 4));
    }
    // Stage q-tile pre-scaled by 1/T: 128 rows x 16 float4 = 2048 items, 8 iters.
#pragma unroll
    for (int i = t; i < kC * 16; i += 256) {
        const int c  = i >> 4;
        const int x4 = (i & 15) << 2;
        float4 qv = *reinterpret_cast<const float4*>(qb + (size_t)c * kN + min(q0 + x4, kN - 4));
        qv.x *= kInvT; qv.y *= kInvT; qv.z *= kInvT; qv.w *= kInvT;
        *reinterpret_cast<float4*>(&qs[c][x4]) = qv;
    }
    __syncthreads();

    const int qx = (t & 15) << 2;       // 16 q-groups * 4
    const int kx = (t >> 4) << 1;       // 16 k-groups * 2

    float acc[2][4];
#pragma unroll
    for (int i = 0; i < 2; ++i)
#pragma unroll
        for (int j = 0; j < 4; ++j) acc[i][j] = 0.0f;

#pragma unroll 4
    for (int c = 0; c < kC; ++c) {
        const float2 kv = *reinterpret_cast<const float2*>(&ks[c][kx]);
        const float4 qv = *reinterpret_cast<const float4*>(&qs[c][qx]);
        const float kf[2] = {kv.x, kv.y};
        const float qf[4] = {qv.x, qv.y, qv.z, qv.w};
#pragma unroll
        for (int i = 0; i < 2; ++i)
#pragma unroll
            for (int j = 0; j < 4; ++j)
                acc[i][j] += fabsf(qf[j] - kf[i]);  // v_sub + v_add(abs) = 2 VALU
    }

    const int qcol = q0 + qx;
    if (qcol < kN) {
#pragma unroll
        for (int i = 0; i < 2; ++i) {
            const int krow = k0 + kx + i;
            if (krow < kN) {
                *reinterpret_cast<float4*>(&D[((size_t)b * kN + krow) * kN + qcol]) =
                    make_float4(acc[i][0], acc[i][1], acc[i][2], acc[i][3]);
            }
        }
    }
}

// ================= Kernel 2: in-place row softmax over q (mean folded) =================
// One block per (b,k) row; 1568 blocks; float4 per thread (196 of 256 active).
__global__ __launch_bounds__(256) void softmax_kernel(float* __restrict__ A) {
    float4* A4 = reinterpret_cast<float4*>(A + (size_t)blockIdx.x * kN);
    const int t = threadIdx.x;
    const int lane = t & 63, wid = t >> 6;
    const bool act = t < (kN / 4);  // 196
    __shared__ float xred[4];

    float4 x = make_float4(-1e30f, -1e30f, -1e30f, -1e30f);
    if (act) x = A4[t];

    float m = fmaxf(fmaxf(x.x, x.y), fmaxf(x.z, x.w));
    m = wave_max(m);
    if (lane == 0) xred[wid] = m;
    __syncthreads();
    m = fmaxf(fmaxf(xred[0], xred[1]), fmaxf(xred[2], xred[3]));
    __syncthreads();

    float4 p;
    p.x = __expf((x.x - m) * kInvC);
    p.y = __expf((x.y - m) * kInvC);
    p.z = __expf((x.z - m) * kInvC);
    p.w = __expf((x.w - m) * kInvC);
    float lsum = p.x + p.y + p.z + p.w;  // inactive lanes: exp(-huge)=0
    lsum = wave_sum(lsum);
    if (lane == 0) xred[wid] = lsum;
    __syncthreads();
    const float inv = 1.0f / (xred[0] + xred[1] + xred[2] + xred[3]);
    if (act) {
        p.x *= inv; p.y *= inv; p.z *= inv; p.w *= inv;
        A4[t] = p;
    }
}

// ================= Kernel 3: out[b,c,k] += sum_q v[b,c,q] * attn[b,k,q] =================
// 64c x 64k tile, 4c x 4k per thread, qsplit 14 (56 q each, 2 chunks of 28).
// Grid = 2b * 2ct * 13kt * 14qs = 728. Conflict-free transposed staging
// (float4 global reads + scalar LDS writes with 2-way bank pattern = free).
constexpr int BKT = 64;
constexpr int NKT2 = (kN + BKT - 1) / BKT;  // 13
constexpr int QSP = 14;
constexpr int QPB = kN / QSP;               // 56
constexpr int QCH = 28;
constexpr int BSTR = 68;

__global__ __launch_bounds__(256) void bmm_kernel(const float* __restrict__ vg,
                                                  const float* __restrict__ attn,
                                                  float* __restrict__ out) {
    int bid = blockIdx.x;
    const int qs = bid % QSP;   bid /= QSP;
    const int kt = bid % NKT2;  bid /= NKT2;
    const int ct = bid & 1;     bid >>= 1;
    const int b  = bid;
    const int k0 = kt * BKT;
    const int c0 = ct * 64;
    const int qb0 = qs * QPB;
    const int t  = threadIdx.x;

    __shared__ float vT[QCH][BSTR];
    __shared__ float aT[QCH][BSTR];

    const int cc = t >> 2;        // staging row 0..63
    const int j1 = t & 3;         // q-float4 group 0..3
    const int j2 = j1 + 4;        // 4..6 valid
    const int c0l = (t & 15) << 2;
    const int k0l = (t >> 4) << 2;

    float acc[4][4];
#pragma unroll
    for (int i = 0; i < 4; ++i)
#pragma unroll
        for (int j = 0; j < 4; ++j) acc[i][j] = 0.0f;

    const float* vb = vg + ((size_t)b * kC + c0) * kN;
    const float* ab = attn + (size_t)b * kN * kN;
    const int krow_st = min(k0 + cc, kN - 1);  // clamped pad rows never stored

    for (int qc = 0; qc < QPB; qc += QCH) {
        const int q0 = qb0 + qc;
        // prefetch (overlaps previous chunk's compute)
        const float4 vv1 = *reinterpret_cast<const float4*>(vb + (size_t)cc * kN + q0 + 4 * j1);
        const float4 av1 = *reinterpret_cast<const float4*>(ab + (size_t)krow_st * kN + q0 + 4 * j1);
        float4 vv2, av2;
        const bool has2 = (j2 < 7);
        if (has2) {
            vv2 = *reinterpret_cast<const float4*>(vb + (size_t)cc * kN + q0 + 4 * j2);
            av2 = *reinterpret_cast<const float4*>(ab + (size_t)krow_st * kN + q0 + 4 * j2);
        }
        __syncthreads();  // previous chunk's LDS reads done
        {
            const int r1 = 4 * j1;
            vT[r1 + 0][cc] = vv1.x; vT[r1 + 1][cc] = vv1.y;
            vT[r1 + 2][cc] = vv1.z; vT[r1 + 3][cc] = vv1.w;
            aT[r1 + 0][cc] = av1.x; aT[r1 + 1][cc] = av1.y;
            aT[r1 + 2][cc] = av1.z; aT[r1 + 3][cc] = av1.w;
            if (has2) {
                const int r2 = 4 * j2;
                vT[r2 + 0][cc] = vv2.x; vT[r2 + 1][cc] = vv2.y;
                vT[r2 + 2][cc] = vv2.z; vT[r2 + 3][cc] = vv2.w;
                aT[r2 + 0][cc] = av2.x; aT[r2 + 1][cc] = av2.y;
                aT[r2 + 2][cc] = av2.z; aT[r2 + 3][cc] = av2.w;
            }
        }
        __syncthreads();

#pragma unroll
        for (int qq = 0; qq < QCH; ++qq) {
            const float4 vf4 = *reinterpret_cast<const float4*>(&vT[qq][c0l]);
            const float4 af4 = *reinterpret_cast<const float4*>(&aT[qq][k0l]);
            const float vf[4] = {vf4.x, vf4.y, vf4.z, vf4.w};
            const float af[4] = {af4.x, af4.y, af4.z, af4.w};
#pragma unroll
            for (int i = 0; i < 4; ++i)
#pragma unroll
                for (int j = 0; j < 4; ++j) acc[i][j] += vf[i] * af[j];
        }
    }

#pragma unroll
    for (int i = 0; i < 4; ++i) {
        const int c = c0 + c0l + i;
#pragma unroll
        for (int j = 0; j < 4; ++j) {
            const int krow = k0 + k0l + j;
            if (krow < kN)
                atomicAdd(&out[((size_t)b * kC + c) * kN + krow], acc[i][j]);
        }
    }
}

extern "C" void kernel_launch(void* const* d_in, const int* in_sizes, int n_in,
                              void* d_out, int out_size, void* d_ws, size_t ws_size,
                              hipStream_t stream) {
    const float* q = (const float*)d_in[0];
    const float* k = (const float*)d_in[1];
    const float* v = (const float*)d_in[2];

    float* out  = (float*)d_out;               // [B, C, N]
    float* attn = out + (size_t)kB * kC * kN;  // [B, N, N]

    // d_ws intentionally unused. `out` is zeroed inside dist_kernel (stream-ordered
    // before bmm_kernel's atomic accumulation).
    dist_kernel<<<kB * NKT * NQT, 256, 0, stream>>>(q, k, attn, out);
    softmax_kernel<<<kB * kN, 256, 0, stream>>>(attn);
    bmm_kernel<<<kB * 2 * NKT2 * QSP, 256, 0, stream>>>(v, attn, out);
}

// Round 7
// 93.795 us; speedup vs baseline: 1.7198x; 1.3989x over previous
//
#include <hip/hip_runtime.h>
#include <math.h>

// Problem constants
constexpr int kB = 2;
constexpr int kC = 128;
constexpr int kN = 784;
constexpr float kInvT = 1.0f / 11.313708498984761f;  // 1/sqrt(C)
constexpr float kInvC = 1.0f / 128.0f;

constexpr size_t kOutElems  = (size_t)kB * kC * kN;  // 200704
constexpr size_t kAttnElems = (size_t)kB * kN * kN;  // 1229312

__device__ inline float wave_max(float v) {
#pragma unroll
    for (int o = 32; o > 0; o >>= 1) v = fmaxf(v, __shfl_xor(v, o, 64));
    return v;
}
__device__ inline float wave_sum(float v) {
#pragma unroll
    for (int o = 32; o > 0; o >>= 1) v += __shfl_xor(v, o, 64);
    return v;
}

// ================= Kernel 1: D[b,k,q] = sum_c |q[c,q]/T - k[c,k]| (raw sums) =================
// 32k x 64q tile, c split in 2 halves (LDS 26.6 KB -> 6 blocks/CU resident).
// Grid = 2b * 2ch * 25kt * 13qt = 1300 (~5 blocks/CU = 20 waves/CU for latency hiding).
// Thread: 2k x 4q. Half 0 -> attn region, half 1 -> ws; softmax sums them.
constexpr int TK = 32;
constexpr int TQ = 64;
constexpr int NKT = (kN + TK - 1) / TK;  // 25
constexpr int NQT = (kN + TQ - 1) / TQ;  // 13
constexpr int CSP = 2;
constexpr int CH = kC / CSP;             // 64
constexpr int KSTR = 36;
constexpr int QSTR = 68;

template <bool USE_WS>
__global__ __launch_bounds__(256) void dist_kernel(const float* __restrict__ qg,
                                                   const float* __restrict__ kg,
                                                   float* __restrict__ D0,
                                                   float* __restrict__ D1) {
    int bid = blockIdx.x;
    const int qt = bid % NQT; bid /= NQT;
    const int kt = bid % NKT; bid /= NKT;
    const int ch = bid & 1;   bid >>= 1;
    const int b  = bid;
    const int k0 = kt * TK;
    const int q0 = qt * TQ;
    const int t  = threadIdx.x;

    __shared__ float ks[CH][KSTR];  // 9.2 KB
    __shared__ float qs[CH][QSTR];  // 17.4 KB

    const float* kb = kg + ((size_t)b * kC + ch * CH) * kN;
    const float* qb = qg + ((size_t)b * kC + ch * CH) * kN;

    // Stage k-tile: 64 rows x 8 float4 = 512 items (2 iters).
#pragma unroll
    for (int i = t; i < CH * 8; i += 256) {
        const int c  = i >> 3;
        const int x4 = (i & 7) << 2;
        *reinterpret_cast<float4*>(&ks[c][x4]) =
            *reinterpret_cast<const float4*>(kb + (size_t)c * kN + min(k0 + x4, kN - 4));
    }
    // Stage q-tile pre-scaled by 1/T: 64 rows x 16 float4 = 1024 items (4 iters).
#pragma unroll
    for (int i = t; i < CH * 16; i += 256) {
        const int c  = i >> 4;
        const int x4 = (i & 15) << 2;
        float4 qv = *reinterpret_cast<const float4*>(qb + (size_t)c * kN + min(q0 + x4, kN - 4));
        qv.x *= kInvT; qv.y *= kInvT; qv.z *= kInvT; qv.w *= kInvT;
        *reinterpret_cast<float4*>(&qs[c][x4]) = qv;
    }
    __syncthreads();

    const int qx = (t & 15) << 2;  // 16 q-groups (float4, distinct per wave)
    const int kx = (t >> 4) << 1;  // k float2, 16-lane broadcast

    float acc[2][4];
#pragma unroll
    for (int i = 0; i < 2; ++i)
#pragma unroll
        for (int j = 0; j < 4; ++j) acc[i][j] = 0.0f;

#pragma unroll 4
    for (int c = 0; c < CH; ++c) {
        const float2 kv = *reinterpret_cast<const float2*>(&ks[c][kx]);
        const float4 qv = *reinterpret_cast<const float4*>(&qs[c][qx]);
        const float kf[2] = {kv.x, kv.y};
        const float qf[4] = {qv.x, qv.y, qv.z, qv.w};
#pragma unroll
        for (int i = 0; i < 2; ++i)
#pragma unroll
            for (int j = 0; j < 4; ++j)
                acc[i][j] += fabsf(qf[j] - kf[i]);
    }

    const int qcol = q0 + qx;
    if (qcol < kN) {
        float* dst = (USE_WS && ch) ? D1 : D0;
#pragma unroll
        for (int i = 0; i < 2; ++i) {
            const int krow = k0 + kx + i;
            if (krow < kN) {
                const size_t off = ((size_t)b * kN + krow) * kN + qcol;
                if (USE_WS) {
                    *reinterpret_cast<float4*>(dst + off) =
                        make_float4(acc[i][0], acc[i][1], acc[i][2], acc[i][3]);
                } else {
                    atomicAdd(&D0[off + 0], acc[i][0]);
                    atomicAdd(&D0[off + 1], acc[i][1]);
                    atomicAdd(&D0[off + 2], acc[i][2]);
                    atomicAdd(&D0[off + 3], acc[i][3]);
                }
            }
        }
    }
}

// ================= Kernel 2: row softmax over q (sums the two c-halves) =================
template <bool SUM2>
__global__ __launch_bounds__(256) void softmax_kernel(float* __restrict__ A,
                                                      const float* __restrict__ W) {
    const size_t row = (size_t)blockIdx.x * kN;
    float4* A4 = reinterpret_cast<float4*>(A + row);
    const float4* W4 = reinterpret_cast<const float4*>(W + row);
    const int t = threadIdx.x;
    const int lane = t & 63, wid = t >> 6;
    const bool act = t < (kN / 4);  // 196
    __shared__ float xred[4];

    float4 x = make_float4(-1e30f, -1e30f, -1e30f, -1e30f);
    if (act) {
        x = A4[t];
        if (SUM2) {
            const float4 w = W4[t];
            x.x += w.x; x.y += w.y; x.z += w.z; x.w += w.w;
        }
    }

    float m = fmaxf(fmaxf(x.x, x.y), fmaxf(x.z, x.w));
    m = wave_max(m);
    if (lane == 0) xred[wid] = m;
    __syncthreads();
    m = fmaxf(fmaxf(xred[0], xred[1]), fmaxf(xred[2], xred[3]));
    __syncthreads();

    float4 p;
    p.x = __expf((x.x - m) * kInvC);
    p.y = __expf((x.y - m) * kInvC);
    p.z = __expf((x.z - m) * kInvC);
    p.w = __expf((x.w - m) * kInvC);
    float lsum = p.x + p.y + p.z + p.w;  // inactive: exp(-huge)=0
    lsum = wave_sum(lsum);
    if (lane == 0) xred[wid] = lsum;
    __syncthreads();
    const float inv = 1.0f / (xred[0] + xred[1] + xred[2] + xred[3]);
    if (act) {
        p.x *= inv; p.y *= inv; p.z *= inv; p.w *= inv;
        A4[t] = p;
    }
}

// ================= Kernel 3: partial[qs][b,c,k] = sum_{q in slice} v[b,c,q]*attn[b,k,q] =================
// 64c x 64k tile, 4c x 4k per thread, qsplit 14 (56 q each, 2 chunks of 28).
// Grid = 2b * 2ct * 13kt * 14qs = 728. NO atomics: clean float4 partial stores
// (k lane-fast -> 256B coalesced segments). ATOMIC=true is the small-ws fallback.
constexpr int BKT = 64;
constexpr int NKT2 = (kN + BKT - 1) / BKT;  // 13
constexpr int QSP = 14;
constexpr int QPB = kN / QSP;               // 56
constexpr int QCH = 28;
constexpr int BSTR = 68;

template <bool ATOMIC>
__global__ __launch_bounds__(256) void bmm_stage1(const float* __restrict__ vg,
                                                  const float* __restrict__ attn,
                                                  float* __restrict__ P) {
    int bid = blockIdx.x;
    const int qs = bid % QSP;   bid /= QSP;
    const int kt = bid % NKT2;  bid /= NKT2;
    const int ct = bid & 1;     bid >>= 1;
    const int b  = bid;
    const int k0 = kt * BKT;
    const int c0 = ct * 64;
    const int qb0 = qs * QPB;
    const int t  = threadIdx.x;

    __shared__ float vT[QCH][BSTR];
    __shared__ float aT[QCH][BSTR];

    const int cc = t >> 2;          // staging row 0..63
    const int j1 = t & 3;           // q-float4 group 0..3
    const int j2 = j1 + 4;          // 4..6 valid
    const int c0l = (t >> 4) << 2;  // c: wave-broadcast reads
    const int k0l = (t & 15) << 2;  // k: lane-fast (coalesced stores)

    float acc[4][4];
#pragma unroll
    for (int i = 0; i < 4; ++i)
#pragma unroll
        for (int j = 0; j < 4; ++j) acc[i][j] = 0.0f;

    const float* vb = vg + ((size_t)b * kC + c0) * kN;
    const float* ab = attn + (size_t)b * kN * kN;
    const int krow_st = min(k0 + cc, kN - 1);  // clamped junk rows never stored

    for (int qc = 0; qc < QPB; qc += QCH) {
        const int q0 = qb0 + qc;
        const float4 vv1 = *reinterpret_cast<const float4*>(vb + (size_t)cc * kN + q0 + 4 * j1);
        const float4 av1 = *reinterpret_cast<const float4*>(ab + (size_t)krow_st * kN + q0 + 4 * j1);
        float4 vv2, av2;
        const bool has2 = (j2 < 7);
        if (has2) {
            vv2 = *reinterpret_cast<const float4*>(vb + (size_t)cc * kN + q0 + 4 * j2);
            av2 = *reinterpret_cast<const float4*>(ab + (size_t)krow_st * kN + q0 + 4 * j2);
        }
        __syncthreads();
        {
            const int r1 = 4 * j1;
            vT[r1 + 0][cc] = vv1.x; vT[r1 + 1][cc] = vv1.y;
            vT[r1 + 2][cc] = vv1.z; vT[r1 + 3][cc] = vv1.w;
            aT[r1 + 0][cc] = av1.x; aT[r1 + 1][cc] = av1.y;
            aT[r1 + 2][cc] = av1.z; aT[r1 + 3][cc] = av1.w;
            if (has2) {
                const int r2 = 4 * j2;
                vT[r2 + 0][cc] = vv2.x; vT[r2 + 1][cc] = vv2.y;
                vT[r2 + 2][cc] = vv2.z; vT[r2 + 3][cc] = vv2.w;
                aT[r2 + 0][cc] = av2.x; aT[r2 + 1][cc] = av2.y;
                aT[r2 + 2][cc] = av2.z; aT[r2 + 3][cc] = av2.w;
            }
        }
        __syncthreads();

#pragma unroll
        for (int qq = 0; qq < QCH; ++qq) {
            const float4 vf4 = *reinterpret_cast<const float4*>(&vT[qq][c0l]);
            const float4 af4 = *reinterpret_cast<const float4*>(&aT[qq][k0l]);
            const float vf[4] = {vf4.x, vf4.y, vf4.z, vf4.w};
            const float af[4] = {af4.x, af4.y, af4.z, af4.w};
#pragma unroll
            for (int i = 0; i < 4; ++i)
#pragma unroll
                for (int j = 0; j < 4; ++j) acc[i][j] += vf[i] * af[j];
        }
    }

    if (ATOMIC) {
#pragma unroll
        for (int i = 0; i < 4; ++i) {
            const int c = c0 + c0l + i;
#pragma unroll
            for (int j = 0; j < 4; ++j) {
                const int krow = k0 + k0l + j;
                if (krow < kN)
                    atomicAdd(&P[((size_t)b * kC + c) * kN + krow], acc[i][j]);
            }
        }
    } else if (k0 + k0l < kN) {  // kN%4==0: float4 fully valid or fully out
#pragma unroll
        for (int i = 0; i < 4; ++i) {
            const int c = c0 + c0l + i;
            *reinterpret_cast<float4*>(
                P + (((size_t)qs * kB + b) * kC + c) * kN + k0 + k0l) =
                make_float4(acc[i][0], acc[i][1], acc[i][2], acc[i][3]);
        }
    }
}

// ================= Kernel 4: out = sum_qs partial[qs] =================
// 196 blocks x 256 threads; one float4 per thread; slices L2/L3-resident.
__global__ __launch_bounds__(256) void reduce_kernel(const float* __restrict__ P,
                                                     float* __restrict__ out) {
    const int idx = blockIdx.x * 256 + threadIdx.x;  // < 50176 exactly
    const float4* p = reinterpret_cast<const float4*>(P) + idx;
    float4 s = p[0];
#pragma unroll
    for (int qs = 1; qs < QSP; ++qs) {
        const float4 v = p[(size_t)qs * (kOutElems / 4)];
        s.x += v.x; s.y += v.y; s.z += v.z; s.w += v.w;
    }
    reinterpret_cast<float4*>(out)[idx] = s;
}

extern "C" void kernel_launch(void* const* d_in, const int* in_sizes, int n_in,
                              void* d_out, int out_size, void* d_ws, size_t ws_size,
                              hipStream_t stream) {
    const float* q = (const float*)d_in[0];
    const float* k = (const float*)d_in[1];
    const float* v = (const float*)d_in[2];

    float* out  = (float*)d_out;               // [B, C, N]
    float* attn = out + kOutElems;             // [B, N, N]
    float* P    = (float*)d_ws;                // [QSP][B, C, N] partials
    float* D1   = P + (size_t)QSP * kOutElems; // [B, N, N] second dist half

    const size_t need = ((size_t)QSP * kOutElems + kAttnElems) * sizeof(float);

    if (ws_size >= need) {
        dist_kernel<true><<<kB * CSP * NKT * NQT, 256, 0, stream>>>(q, k, attn, D1);
        softmax_kernel<true><<<kB * kN, 256, 0, stream>>>(attn, D1);
        bmm_stage1<false><<<kB * 2 * NKT2 * QSP, 256, 0, stream>>>(v, attn, P);
        reduce_kernel<<<(int)(kOutElems / 4 / 256), 256, 0, stream>>>(P, out);
    } else {
        // Fallback without workspace: accumulate via atomics.
        hipMemsetAsync(attn, 0, kAttnElems * sizeof(float), stream);
        hipMemsetAsync(out, 0, kOutElems * sizeof(float), stream);
        dist_kernel<false><<<kB * CSP * NKT * NQT, 256, 0, stream>>>(q, k, attn, nullptr);
        softmax_kernel<false><<<kB * kN, 256, 0, stream>>>(attn, attn);
        bmm_stage1<true><<<kB * 2 * NKT2 * QSP, 256, 0, stream>>>(v, attn, out);
    }
}

// Round 8
// 93.145 us; speedup vs baseline: 1.7318x; 1.0070x over previous
//
#include <hip/hip_runtime.h>
#include <math.h>

// Problem constants
constexpr int kB = 2;
constexpr int kC = 128;
constexpr int kN = 784;
constexpr float kInvT = 1.0f / 11.313708498984761f;  // 1/sqrt(C)
constexpr float kInvC = 1.0f / 128.0f;

constexpr size_t kOutElems  = (size_t)kB * kC * kN;  // 200704
constexpr size_t kAttnElems = (size_t)kB * kN * kN;  // 1229312

__device__ inline float wave_max(float v) {
#pragma unroll
    for (int o = 32; o > 0; o >>= 1) v = fmaxf(v, __shfl_xor(v, o, 64));
    return v;
}
__device__ inline float wave_sum(float v) {
#pragma unroll
    for (int o = 32; o > 0; o >>= 1) v += __shfl_xor(v, o, 64);
    return v;
}

// ================= Kernel 1: D[b,k,q] = sum_c |q[c,q]/T - k[c,k]| (raw sums) =================
// 64k x 64q tile, 4k x 4q per thread (16 indep accs; VALU:LDS = 64:24 cyc/c-iter),
// c split in 2 halves. LDS 34.8 KB -> 4 blocks/CU resident; grid 2b*2ch*13*13 = 676.
// k-operand: b128 16-lane broadcast; q-operand: b128 2-way (free). Half 0 -> attn
// region, half 1 -> ws; softmax sums the halves.
constexpr int TK = 64;
constexpr int TQ = 64;
constexpr int NKT = (kN + TK - 1) / TK;  // 13
constexpr int NQT = (kN + TQ - 1) / TQ;  // 13
constexpr int CSP = 2;
constexpr int CH = kC / CSP;             // 64
constexpr int DSTR = 68;                 // 64+4 pad

template <bool USE_WS>
__global__ __launch_bounds__(256) void dist_kernel(const float* __restrict__ qg,
                                                   const float* __restrict__ kg,
                                                   float* __restrict__ D0,
                                                   float* __restrict__ D1) {
    int bid = blockIdx.x;
    const int qt = bid % NQT; bid /= NQT;
    const int kt = bid % NKT; bid /= NKT;
    const int ch = bid & 1;   bid >>= 1;
    const int b  = bid;
    const int k0 = kt * TK;
    const int q0 = qt * TQ;
    const int t  = threadIdx.x;

    __shared__ float ks[CH][DSTR];  // 17.4 KB
    __shared__ float qs[CH][DSTR];  // 17.4 KB

    const float* kb = kg + ((size_t)b * kC + ch * CH) * kN;
    const float* qb = qg + ((size_t)b * kC + ch * CH) * kN;

    // Stage both 64x64 tiles: 64 rows x 16 float4 each (4 iters per array).
#pragma unroll
    for (int i = t; i < CH * 16; i += 256) {
        const int c  = i >> 4;
        const int x4 = (i & 15) << 2;
        *reinterpret_cast<float4*>(&ks[c][x4]) =
            *reinterpret_cast<const float4*>(kb + (size_t)c * kN + min(k0 + x4, kN - 4));
        float4 qv = *reinterpret_cast<const float4*>(qb + (size_t)c * kN + min(q0 + x4, kN - 4));
        qv.x *= kInvT; qv.y *= kInvT; qv.z *= kInvT; qv.w *= kInvT;
        *reinterpret_cast<float4*>(&qs[c][x4]) = qv;
    }
    __syncthreads();

    const int qx = (t & 15) << 2;  // 16 q-groups (b128, 2-way across half-wave = free)
    const int kx = (t >> 4) << 2;  // 16 k-groups (b128, 16-lane broadcast)

    float acc[4][4];
#pragma unroll
    for (int i = 0; i < 4; ++i)
#pragma unroll
        for (int j = 0; j < 4; ++j) acc[i][j] = 0.0f;

#pragma unroll 4
    for (int c = 0; c < CH; ++c) {
        const float4 kv = *reinterpret_cast<const float4*>(&ks[c][kx]);
        const float4 qv = *reinterpret_cast<const float4*>(&qs[c][qx]);
        const float kf[4] = {kv.x, kv.y, kv.z, kv.w};
        const float qf[4] = {qv.x, qv.y, qv.z, qv.w};
#pragma unroll
        for (int i = 0; i < 4; ++i)
#pragma unroll
            for (int j = 0; j < 4; ++j)
                acc[i][j] += fabsf(qf[j] - kf[i]);  // v_sub + v_add(abs) = 2 VALU
    }

    const int qcol = q0 + qx;
    if (qcol < kN) {
        float* dst = (USE_WS && ch) ? D1 : D0;
#pragma unroll
        for (int i = 0; i < 4; ++i) {
            const int krow = k0 + kx + i;
            if (krow < kN) {
                const size_t off = ((size_t)b * kN + krow) * kN + qcol;
                if (USE_WS) {
                    *reinterpret_cast<float4*>(dst + off) =
                        make_float4(acc[i][0], acc[i][1], acc[i][2], acc[i][3]);
                } else {
                    atomicAdd(&D0[off + 0], acc[i][0]);
                    atomicAdd(&D0[off + 1], acc[i][1]);
                    atomicAdd(&D0[off + 2], acc[i][2]);
                    atomicAdd(&D0[off + 3], acc[i][3]);
                }
            }
        }
    }
}

// ================= Kernel 2: row softmax over q (sums the two c-halves) =================
template <bool SUM2>
__global__ __launch_bounds__(256) void softmax_kernel(float* __restrict__ A,
                                                      const float* __restrict__ W) {
    const size_t row = (size_t)blockIdx.x * kN;
    float4* A4 = reinterpret_cast<float4*>(A + row);
    const float4* W4 = reinterpret_cast<const float4*>(W + row);
    const int t = threadIdx.x;
    const int lane = t & 63, wid = t >> 6;
    const bool act = t < (kN / 4);  // 196
    __shared__ float xred[4];

    float4 x = make_float4(-1e30f, -1e30f, -1e30f, -1e30f);
    if (act) {
        x = A4[t];
        if (SUM2) {
            const float4 w = W4[t];
            x.x += w.x; x.y += w.y; x.z += w.z; x.w += w.w;
        }
    }

    float m = fmaxf(fmaxf(x.x, x.y), fmaxf(x.z, x.w));
    m = wave_max(m);
    if (lane == 0) xred[wid] = m;
    __syncthreads();
    m = fmaxf(fmaxf(xred[0], xred[1]), fmaxf(xred[2], xred[3]));
    __syncthreads();

    float4 p;
    p.x = __expf((x.x - m) * kInvC);
    p.y = __expf((x.y - m) * kInvC);
    p.z = __expf((x.z - m) * kInvC);
    p.w = __expf((x.w - m) * kInvC);
    float lsum = p.x + p.y + p.z + p.w;  // inactive: exp(-huge)=0
    lsum = wave_sum(lsum);
    if (lane == 0) xred[wid] = lsum;
    __syncthreads();
    const float inv = 1.0f / (xred[0] + xred[1] + xred[2] + xred[3]);
    if (act) {
        p.x *= inv; p.y *= inv; p.z *= inv; p.w *= inv;
        A4[t] = p;
    }
}

// ================= Kernel 3: partial[qs][b,c,k] = sum_{q in slice} v[b,c,q]*attn[b,k,q] =================
// 64c x 64k tile, 4c x 4k per thread, qsplit 14 (56 q each, 2 chunks of 28).
// Grid = 2b * 2ct * 13kt * 14qs = 728. NO atomics: clean float4 partial stores
// (k lane-fast -> 256B coalesced segments). ATOMIC=true is the small-ws fallback.
constexpr int BKT = 64;
constexpr int NKT2 = (kN + BKT - 1) / BKT;  // 13
constexpr int QSP = 14;
constexpr int QPB = kN / QSP;               // 56
constexpr int QCH = 28;
constexpr int BSTR = 68;

template <bool ATOMIC>
__global__ __launch_bounds__(256) void bmm_stage1(const float* __restrict__ vg,
                                                  const float* __restrict__ attn,
                                                  float* __restrict__ P) {
    int bid = blockIdx.x;
    const int qs = bid % QSP;   bid /= QSP;
    const int kt = bid % NKT2;  bid /= NKT2;
    const int ct = bid & 1;     bid >>= 1;
    const int b  = bid;
    const int k0 = kt * BKT;
    const int c0 = ct * 64;
    const int qb0 = qs * QPB;
    const int t  = threadIdx.x;

    __shared__ float vT[QCH][BSTR];
    __shared__ float aT[QCH][BSTR];

    const int cc = t >> 2;          // staging row 0..63
    const int j1 = t & 3;           // q-float4 group 0..3
    const int j2 = j1 + 4;          // 4..6 valid
    const int c0l = (t >> 4) << 2;  // c: wave-broadcast reads
    const int k0l = (t & 15) << 2;  // k: lane-fast (coalesced stores)

    float acc[4][4];
#pragma unroll
    for (int i = 0; i < 4; ++i)
#pragma unroll
        for (int j = 0; j < 4; ++j) acc[i][j] = 0.0f;

    const float* vb = vg + ((size_t)b * kC + c0) * kN;
    const float* ab = attn + (size_t)b * kN * kN;
    const int krow_st = min(k0 + cc, kN - 1);  // clamped junk rows never stored

    for (int qc = 0; qc < QPB; qc += QCH) {
        const int q0 = qb0 + qc;
        const float4 vv1 = *reinterpret_cast<const float4*>(vb + (size_t)cc * kN + q0 + 4 * j1);
        const float4 av1 = *reinterpret_cast<const float4*>(ab + (size_t)krow_st * kN + q0 + 4 * j1);
        float4 vv2, av2;
        const bool has2 = (j2 < 7);
        if (has2) {
            vv2 = *reinterpret_cast<const float4*>(vb + (size_t)cc * kN + q0 + 4 * j2);
            av2 = *reinterpret_cast<const float4*>(ab + (size_t)krow_st * kN + q0 + 4 * j2);
        }
        __syncthreads();
        {
            const int r1 = 4 * j1;
            vT[r1 + 0][cc] = vv1.x; vT[r1 + 1][cc] = vv1.y;
            vT[r1 + 2][cc] = vv1.z; vT[r1 + 3][cc] = vv1.w;
            aT[r1 + 0][cc] = av1.x; aT[r1 + 1][cc] = av1.y;
            aT[r1 + 2][cc] = av1.z; aT[r1 + 3][cc] = av1.w;
            if (has2) {
                const int r2 = 4 * j2;
                vT[r2 + 0][cc] = vv2.x; vT[r2 + 1][cc] = vv2.y;
                vT[r2 + 2][cc] = vv2.z; vT[r2 + 3][cc] = vv2.w;
                aT[r2 + 0][cc] = av2.x; aT[r2 + 1][cc] = av2.y;
                aT[r2 + 2][cc] = av2.z; aT[r2 + 3][cc] = av2.w;
            }
        }
        __syncthreads();

#pragma unroll
        for (int qq = 0; qq < QCH; ++qq) {
            const float4 vf4 = *reinterpret_cast<const float4*>(&vT[qq][c0l]);
            const float4 af4 = *reinterpret_cast<const float4*>(&aT[qq][k0l]);
            const float vf[4] = {vf4.x, vf4.y, vf4.z, vf4.w};
            const float af[4] = {af4.x, af4.y, af4.z, af4.w};
#pragma unroll
            for (int i = 0; i < 4; ++i)
#pragma unroll
                for (int j = 0; j < 4; ++j) acc[i][j] += vf[i] * af[j];
        }
    }

    if (ATOMIC) {
#pragma unroll
        for (int i = 0; i < 4; ++i) {
            const int c = c0 + c0l + i;
#pragma unroll
            for (int j = 0; j < 4; ++j) {
                const int krow = k0 + k0l + j;
                if (krow < kN)
                    atomicAdd(&P[((size_t)b * kC + c) * kN + krow], acc[i][j]);
            }
        }
    } else if (k0 + k0l < kN) {  // kN%4==0: float4 fully valid or fully out
#pragma unroll
        for (int i = 0; i < 4; ++i) {
            const int c = c0 + c0l + i;
            *reinterpret_cast<float4*>(
                P + (((size_t)qs * kB + b) * kC + c) * kN + k0 + k0l) =
                make_float4(acc[i][0], acc[i][1], acc[i][2], acc[i][3]);
        }
    }
}

// ================= Kernel 4: out = sum_qs partial[qs] =================
// 196 blocks x 256 threads; one float4 per thread; slices L2/L3-resident.
__global__ __launch_bounds__(256) void reduce_kernel(const float* __restrict__ P,
                                                     float* __restrict__ out) {
    const int idx = blockIdx.x * 256 + threadIdx.x;  // < 50176 exactly
    const float4* p = reinterpret_cast<const float4*>(P) + idx;
    float4 s = p[0];
#pragma unroll
    for (int qs = 1; qs < QSP; ++qs) {
        const float4 v = p[(size_t)qs * (kOutElems / 4)];
        s.x += v.x; s.y += v.y; s.z += v.z; s.w += v.w;
    }
    reinterpret_cast<float4*>(out)[idx] = s;
}

extern "C" void kernel_launch(void* const* d_in, const int* in_sizes, int n_in,
                              void* d_out, int out_size, void* d_ws, size_t ws_size,
                              hipStream_t stream) {
    const float* q = (const float*)d_in[0];
    const float* k = (const float*)d_in[1];
    const float* v = (const float*)d_in[2];

    float* out  = (float*)d_out;               // [B, C, N]
    float* attn = out + kOutElems;             // [B, N, N]
    float* P    = (float*)d_ws;                // [QSP][B, C, N] partials
    float* D1   = P + (size_t)QSP * kOutElems; // [B, N, N] second dist half

    const size_t need = ((size_t)QSP * kOutElems + kAttnElems) * sizeof(float);

    if (ws_size >= need) {
        dist_kernel<true><<<kB * CSP * NKT * NQT, 256, 0, stream>>>(q, k, attn, D1);
        softmax_kernel<true><<<kB * kN, 256, 0, stream>>>(attn, D1);
        bmm_stage1<false><<<kB * 2 * NKT2 * QSP, 256, 0, stream>>>(v, attn, P);
        reduce_kernel<<<(int)(kOutElems / 4 / 256), 256, 0, stream>>>(P, out);
    } else {
        // Fallback without workspace: accumulate via atomics.
        hipMemsetAsync(attn, 0, kAttnElems * sizeof(float), stream);
        hipMemsetAsync(out, 0, kOutElems * sizeof(float), stream);
        dist_kernel<false><<<kB * CSP * NKT * NQT, 256, 0, stream>>>(q, k, attn, nullptr);
        softmax_kernel<false><<<kB * kN, 256, 0, stream>>>(attn, attn);
        bmm_stage1<true><<<kB * 2 * NKT2 * QSP, 256, 0, stream>>>(v, attn, out);
    }
}